// Round 7
// baseline (2024.356 us; speedup 1.0000x reference)
//
#include <hip/hip_runtime.h>
#include <stdint.h>

#define NSZ 2048
#define NLAYERS 4

typedef __attribute__((ext_vector_type(4))) float f32x4;
typedef __attribute__((ext_vector_type(4))) _Float16 f16x4;
typedef __attribute__((ext_vector_type(8))) _Float16 f16x8;

__device__ __forceinline__ void gload_lds16(const void* g, void* l) {
  __builtin_amdgcn_global_load_lds((const __attribute__((address_space(1))) void*)g,
                                   (__attribute__((address_space(3))) void*)l, 16, 0, 0);
}

// ---------------- CSR build ----------------
__global__ void k_zero(int* __restrict__ p, int n) {
  int i = blockIdx.x * 256 + threadIdx.x;
  if (i < n) p[i] = 0;
}

__global__ void k_count(const int* __restrict__ tgt, int E, int* __restrict__ cnt) {
  int e = blockIdx.x * 256 + threadIdx.x;
  if (e < E) atomicAdd(&cnt[tgt[e] & (NSZ - 1)], 1);
}

__global__ __launch_bounds__(1024) void k_scan(
    const int* __restrict__ cntA, int* __restrict__ offA, int* __restrict__ curA,
    float* __restrict__ invA, int EA,
    const int* __restrict__ cntB, int* __restrict__ offB, int* __restrict__ curB,
    float* __restrict__ invB, int EB) {
  const int* cnt; int* off; int* cur; float* inv; int E;
  if (blockIdx.x == 0) { cnt = cntA; off = offA; cur = curA; inv = invA; E = EA; }
  else                 { cnt = cntB; off = offB; cur = curB; inv = invB; E = EB; }
  __shared__ int sa[2048], sb[2048];
  int t = threadIdx.x;
  sa[t] = cnt[t]; sa[t + 1024] = cnt[t + 1024];
  __syncthreads();
  int* s = sa; int* d = sb;
  for (int dd = 1; dd < 2048; dd <<= 1) {
    for (int i = t; i < 2048; i += 1024)
      d[i] = s[i] + ((i >= dd) ? s[i - dd] : 0);
    __syncthreads();
    int* tmp = s; s = d; d = tmp;
  }
  for (int i = t; i < 2048; i += 1024) {
    int o = (i == 0) ? 0 : s[i - 1];
    off[i] = o; cur[i] = o;
    int c = cnt[i];
    inv[i] = 1.0f / (float)((c > 1) ? c : 1);
  }
  if (t == 0) off[2048] = E;
}

__global__ void k_fill(const int* __restrict__ src, const int* __restrict__ tgt, int E,
                       int* __restrict__ cur, int* __restrict__ srcs) {
  int e = blockIdx.x * 256 + threadIdx.x;
  if (e < E) {
    int p = atomicAdd(&cur[tgt[e] & (NSZ - 1)], 1);
    if (p >= 0 && p < E) srcs[p] = src[e] & (NSZ - 1);
  }
}

// ---------------- x [gene,cell] -> A = x^T [cell,gene] fp16 hi/lo, LINEAR ----------------
__global__ __launch_bounds__(256) void k_transpose_cvt(const float* __restrict__ s,
                                                       _Float16* __restrict__ Ah,
                                                       _Float16* __restrict__ Al) {
  __shared__ float tile[64][65];
  const int tid = threadIdx.x;
  const int r0 = blockIdx.y << 6, c0 = blockIdx.x << 6;
#pragma unroll
  for (int it = 0; it < 4; ++it) {
    int e = it * 256 + tid;
    int r = e >> 4;
    int c = (e & 15) << 2;
    f32x4 v = *(const f32x4*)&s[(size_t)(r0 + r) * NSZ + c0 + c];
#pragma unroll
    for (int j = 0; j < 4; ++j) tile[r][c + j] = v[j];
  }
  __syncthreads();
#pragma unroll
  for (int it = 0; it < 4; ++it) {
    int e = it * 256 + tid;
    int r = e >> 4;           // output row within tile (m = cell)
    int c4 = (e & 15) << 2;   // output col chunk (k = gene)
    f16x4 hi, lo;
#pragma unroll
    for (int j = 0; j < 4; ++j) {
      float x = tile[c4 + j][r];
      _Float16 h = (_Float16)x;
      hi[j] = h;
      lo[j] = (_Float16)(x - (float)h);
    }
    int m = c0 + r;
    size_t rowb = (size_t)m << 12;
    int byte = (r0 + c4) << 1;   // linear (A is read direct-to-reg, no LDS swizzle)
    *(f16x4*)((char*)Ah + rowb + byte) = hi;
    *(f16x4*)((char*)Al + rowb + byte) = lo;
  }
}

// ---------------- W [k][n] fp32 -> Bt [nbase+n][k] fp16 hi/lo, swizzled ----------------
__global__ __launch_bounds__(256) void k_cvtB(const float* __restrict__ Wl,
                                              const float* __restrict__ Wr,
                                              _Float16* __restrict__ Bh,
                                              _Float16* __restrict__ Bl) {
  __shared__ float tile[64][65];
  const float* W = blockIdx.z ? Wr : Wl;
  const int nbase = blockIdx.z ? NSZ : 0;
  const int tid = threadIdx.x;
  const int k0 = blockIdx.y << 6;   // input rows (k)
  const int n0 = blockIdx.x << 6;   // input cols (n)
#pragma unroll
  for (int it = 0; it < 4; ++it) {
    int e = it * 256 + tid;
    int r = e >> 4;
    int c = (e & 15) << 2;
    f32x4 v = *(const f32x4*)&W[(size_t)(k0 + r) * NSZ + n0 + c];
#pragma unroll
    for (int j = 0; j < 4; ++j) tile[r][c + j] = v[j];
  }
  __syncthreads();
#pragma unroll
  for (int it = 0; it < 4; ++it) {
    int e = it * 256 + tid;
    int r = e >> 4;            // n within tile (output row)
    int c4 = (e & 15) << 2;    // k within tile (output col chunk)
    f16x4 hi, lo;
#pragma unroll
    for (int j = 0; j < 4; ++j) {
      float x = tile[c4 + j][r];
      _Float16 h = (_Float16)x;
      hi[j] = h;
      lo[j] = (_Float16)(x - (float)h);
    }
    int n = nbase + n0 + r;
    size_t rowb = (size_t)n << 12;
    int byte = ((k0 + c4) << 1) ^ (((n >> 1) & 3) << 4);
    *(f16x4*)((char*)Bh + rowb + byte) = hi;
    *(f16x4*)((char*)Bl + rowb + byte) = lo;
  }
}

// ---------------- fp16x3 split MFMA GEMM: A direct-to-reg, B via LDS ----------------
// 128x128 tile, BK=32, 4 waves 2x2 (each 64x64 = 4x4 frags of 16x16x32_f16).
// C = Ah*Bh + Ah*Bl + Al*Bh, fp32 accumulate. Grid 512 (16 m x 32 n), 2 blocks/CU.
// A fragments: global->VGPR, double-buffered in two NAMED reg sets (unroll-2 loop).
// B: gload_lds staged (swizzled), ds_read_b128. LDS read traffic halved vs R6.
__global__ __launch_bounds__(256, 2) void k_gemm16r(
    const _Float16* __restrict__ Ah, const _Float16* __restrict__ Al,
    const _Float16* __restrict__ Bh, const _Float16* __restrict__ Bl,
    float* __restrict__ C) {
  __shared__ __align__(128) _Float16 lds[2][2][128][32];  // B hi/lo, dbuf, 32 KB
  const int tid = threadIdx.x;
  const int w = tid >> 6;
  const int lane = tid & 63;
  int bid = blockIdx.x;
  bid = ((bid & 7) << 6) | (bid >> 3);     // bijective XCD swizzle (512 = 8*64)
  const int bm = bid & 15;
  const int bn = bid >> 4;
  const int m0 = bm << 7;
  const int n0 = bn << 7;
  const int wm = (w & 1) << 6;
  const int wn = (w >> 1) << 6;

  f32x4 acc[4][4];
#pragma unroll
  for (int i = 0; i < 4; ++i)
#pragma unroll
    for (int j = 0; j < 4; ++j)
#pragma unroll
      for (int r = 0; r < 4; ++r) acc[i][j][r] = 0.f;

  const int srow0 = (w << 5) + (lane >> 2);   // staging row (16 rows/instr)
  const int scol = (lane & 3) << 3;           // halves offset within 32-half chunk
  const int l15 = lane & 15;
  const int ks16 = (lane >> 4) << 4;          // byte offset of this lane's k-slot (B reads)
  const int khalf = (lane >> 4) << 3;         // element offset of k-slot (A reads)

  const size_t boff = (size_t)(n0 + srow0) * NSZ + scol;

// A fragment: direct global->reg, linear layout. dst[f] for K-step base kk.
#define AFR(dst, PTR, f, kk)                                                 \
  dst[f] = *(const f16x8*)((PTR) +                                           \
      (((size_t)(m0 + wm + ((f) << 4) + l15)) << 11) + (size_t)(kk) + khalf);

// B staging part: one gload_lds16 (16 rows), q in {0,1}, hl 0=Bh 1=Bl.
#define SPB(buf, kk, q, hl)                                                  \
  gload_lds16(((hl) ? Bl : Bh) + boff + (size_t)((q) << 4) * NSZ + (size_t)(kk), \
              &lds[buf][hl][((w << 1) + (q)) << 4][0]);

#define RDB2(CUR, f)                                                         \
  { const int rb_ = wn + ((f) << 4) + l15;                                   \
    const int cb_ = ks16 ^ (((rb_ >> 1) & 3) << 4);                          \
    bfh[f] = *(const f16x8*)((const char*)&lds[CUR][0][rb_][0] + cb_);       \
    bfl[f] = *(const f16x8*)((const char*)&lds[CUR][1][rb_][0] + cb_); }

#define TR2(AH, AL, i, j)                                                                 \
  acc[i][j] = __builtin_amdgcn_mfma_f32_16x16x32_f16(AH[i], bfh[j], acc[i][j], 0, 0, 0);  \
  acc[i][j] = __builtin_amdgcn_mfma_f32_16x16x32_f16(AH[i], bfl[j], acc[i][j], 0, 0, 0);  \
  acc[i][j] = __builtin_amdgcn_mfma_f32_16x16x32_f16(AL[i], bfh[j], acc[i][j], 0, 0, 0);

#define QU2(AH, AL, i0, j0)                                                  \
  TR2(AH, AL, i0, j0) TR2(AH, AL, i0, (j0) + 1)                              \
  TR2(AH, AL, (i0) + 1, j0) TR2(AH, AL, (i0) + 1, (j0) + 1)

#define BODY(CAH, CAL, NAH, NAL, CUR, NXT, T, PRE)                           \
  {                                                                          \
    asm volatile("s_waitcnt vmcnt(0)" ::: "memory");                         \
    asm volatile("s_barrier" ::: "memory");                                  \
    const int kn_ = ((T) + 1) << 5;                                          \
    f16x8 bfh[4], bfl[4];                                                    \
    /* P0: stage Bh q0 of next; prefetch next A frags 0,1; read B01; MFMA */ \
    if (PRE) { SPB(NXT, kn_, 0, 0)                                           \
               AFR(NAH, Ah, 0, kn_) AFR(NAL, Al, 0, kn_)                     \
               AFR(NAH, Ah, 1, kn_) AFR(NAL, Al, 1, kn_) }                   \
    RDB2(CUR, 0) RDB2(CUR, 1)                                                \
    __builtin_amdgcn_s_setprio(1);                                           \
    QU2(CAH, CAL, 0, 0)                                                      \
    __builtin_amdgcn_s_setprio(0);                                           \
    asm volatile("s_barrier" ::: "memory");                                  \
    /* P1: stage Bl q0; prefetch next A frags 2,3; read B23; MFMA */         \
    if (PRE) { SPB(NXT, kn_, 0, 1)                                           \
               AFR(NAH, Ah, 2, kn_) AFR(NAL, Al, 2, kn_)                     \
               AFR(NAH, Ah, 3, kn_) AFR(NAL, Al, 3, kn_) }                   \
    RDB2(CUR, 2) RDB2(CUR, 3)                                                \
    __builtin_amdgcn_s_setprio(1);                                           \
    QU2(CAH, CAL, 0, 2)                                                      \
    __builtin_amdgcn_s_setprio(0);                                           \
    asm volatile("s_barrier" ::: "memory");                                  \
    /* P2: stage Bh q1; pure MFMA */                                         \
    if (PRE) { SPB(NXT, kn_, 1, 0) }                                         \
    __builtin_amdgcn_s_setprio(1);                                           \
    QU2(CAH, CAL, 2, 2)                                                      \
    __builtin_amdgcn_s_setprio(0);                                           \
    asm volatile("s_barrier" ::: "memory");                                  \
    /* P3: stage Bl q1; pure MFMA */                                         \
    if (PRE) { SPB(NXT, kn_, 1, 1) }                                         \
    __builtin_amdgcn_s_setprio(1);                                           \
    QU2(CAH, CAL, 2, 0)                                                      \
    __builtin_amdgcn_s_setprio(0);                                           \
  }

  // prologue: A frags for step 0 into even set; stage B buf0
  f16x8 ahe[4], ale[4], aho[4], alo[4];
#pragma unroll
  for (int f = 0; f < 4; ++f) { AFR(ahe, Ah, f, 0) AFR(ale, Al, f, 0) }
  SPB(0, 0, 0, 0) SPB(0, 0, 0, 1) SPB(0, 0, 1, 0) SPB(0, 0, 1, 1)

  for (int tt = 0; tt < 31; ++tt) {
    BODY(ahe, ale, aho, alo, 0, 1, (tt << 1), 1)
    BODY(aho, alo, ahe, ale, 1, 0, ((tt << 1) | 1), 1)
  }
  BODY(ahe, ale, aho, alo, 0, 1, 62, 1)
  BODY(aho, alo, ahe, ale, 1, 0, 63, 0)

#undef AFR
#undef SPB
#undef RDB2
#undef TR2
#undef QU2
#undef BODY

  // C/D layout: col = lane&15, row = (lane>>4)*4 + reg  [m89-verified]
  const int cr = (lane >> 4) << 2;
#pragma unroll
  for (int i = 0; i < 4; ++i)
#pragma unroll
    for (int j = 0; j < 4; ++j) {
      float* Cp = &C[(size_t)(m0 + wm + (i << 4) + cr) * 4096 + n0 + wn + (j << 4) + l15];
#pragma unroll
      for (int r = 0; r < 4; ++r) Cp[(size_t)r * 4096] = acc[i][j][r];
    }
}

// ---------------- fused mean-gather + self + bias + LeakyReLU ----------------
// XCD-pinned feature blocks. Gather: clamped-index predicated 8-batches (no serial
// tail chain). mode 1: write fp16 hi/lo LINEAR transposed (next GEMM's A);
// mode 0: fp32 [target][feature] nontemporal (final output).
__global__ __launch_bounds__(256) void k_fuse(const float* __restrict__ Cb,
                                              const int* __restrict__ off,
                                              const int* __restrict__ srcs,
                                              const float* __restrict__ inv,
                                              const float* __restrict__ bias,
                                              float* __restrict__ outF,
                                              _Float16* __restrict__ oh,
                                              _Float16* __restrict__ ol,
                                              int mode, int E) {
  __shared__ float tile[64][65];
  const int tid = threadIdx.x;
  const int w = tid >> 6;
  const int lane = tid & 63;
  const int lin = blockIdx.x;
  const int xcd = lin & 7;
  const int idx = lin >> 3;
  const int f0 = ((xcd << 2) | (idx & 3)) << 6;   // feature block: L2-resident per XCD
  const int t0 = (idx >> 2) << 6;                 // target block
  const int fc = f0 + lane;
  const float b = bias[fc];

  for (int it = 0; it < 16; ++it) {
    int lt = (w << 4) + it;
    int c = t0 + lt;
    int e0 = off[c], e1 = off[c + 1];
    if (e1 > E) e1 = E;
    if (e0 < 0) e0 = 0;
    float acc = 0.f;
    if (e0 < e1) {
      for (int e = e0; e < e1; e += 8) {
        float p[8];
#pragma unroll
        for (int q = 0; q < 8; ++q) {
          int ee = e + q;
          int ec = (ee < e1) ? ee : (e1 - 1);      // clamp: load always valid
          p[q] = Cb[(size_t)(srcs[ec] & (NSZ - 1)) * 4096 + fc];
        }
#pragma unroll
        for (int q = 0; q < 8; ++q) acc += ((e + q) < e1) ? p[q] : 0.f;
      }
    }
    float val = acc * inv[c] + Cb[(size_t)c * 4096 + 2048 + fc] + b;
    val = (val > 0.f) ? val : 0.01f * val;
    tile[lt][lane] = val;
  }
  __syncthreads();
  for (int it = 0; it < 4; ++it) {
    int f = it * 256 + tid;
    int r = f >> 4;
    int c4 = (f & 15) << 2;
    if (mode) {
      f16x4 hi, lo;
#pragma unroll
      for (int j = 0; j < 4; ++j) {
        float x = tile[c4 + j][r];
        _Float16 h = (_Float16)x;
        hi[j] = h;
        lo[j] = (_Float16)(x - (float)h);
      }
      int m = f0 + r;
      size_t rowb = (size_t)m << 12;
      int byte = (t0 + c4) << 1;   // linear A layout
      *(f16x4*)((char*)oh + rowb + byte) = hi;
      *(f16x4*)((char*)ol + rowb + byte) = lo;
    } else {
      f32x4 v;
#pragma unroll
      for (int j = 0; j < 4; ++j) v[j] = tile[r][c4 + j];
      __builtin_nontemporal_store(v, (f32x4*)&outF[(size_t)(t0 + r) * NSZ + f0 + c4]);
    }
  }
}

extern "C" void kernel_launch(void* const* d_in, const int* in_sizes, int n_in,
                              void* d_out, int out_size, void* d_ws, size_t ws_size,
                              hipStream_t stream) {
  (void)n_in; (void)out_size; (void)ws_size;
  const float* x      = (const float*)d_in[0];
  const int*   knn    = (const int*)d_in[1];
  const int*   ppi    = (const int*)d_in[2];
  const float* col_Wl = (const float*)d_in[3];
  const float* col_bl = (const float*)d_in[4];
  const float* col_Wr = (const float*)d_in[5];
  const float* row_Wl = (const float*)d_in[6];
  const float* row_bl = (const float*)d_in[7];
  const float* row_Wr = (const float*)d_in[8];
  float* out = (float*)d_out;
  const int E_knn = in_sizes[1] / 2;
  const int E_ppi = in_sizes[2] / 2;
  const size_t NN = (size_t)NSZ * NSZ;

  // ---- workspace layout (~81 MB) ----
  char* ws = (char*)d_ws;
  size_t off_b = 0;
  int*   cnt_knn = (int*)(ws + off_b);   off_b += 2048 * 4;
  int*   cnt_ppi = (int*)(ws + off_b);   off_b += 2048 * 4;
  int*   off_knn = (int*)(ws + off_b);   off_b += 2064 * 4;
  int*   off_ppi = (int*)(ws + off_b);   off_b += 2064 * 4;
  int*   cur_knn = (int*)(ws + off_b);   off_b += 2048 * 4;
  int*   cur_ppi = (int*)(ws + off_b);   off_b += 2048 * 4;
  float* inv_knn = (float*)(ws + off_b); off_b += 2048 * 4;
  float* inv_ppi = (float*)(ws + off_b); off_b += 2048 * 4;
  int*   src_knn = (int*)(ws + off_b);   off_b += (size_t)((E_knn + 63) & ~63) * 4;
  int*   src_ppi = (int*)(ws + off_b);   off_b += (size_t)((E_ppi + 63) & ~63) * 4;
  off_b = (off_b + 255) & ~(size_t)255;
  float*     Cbuf = (float*)(ws + off_b);     off_b += NN * 2 * 4;       // 32 MB
  _Float16*  Ahw  = (_Float16*)(ws + off_b);  off_b += NN * 2;           // 8 MB
  _Float16*  Alw  = (_Float16*)(ws + off_b);  off_b += NN * 2;           // 8 MB
  _Float16*  Bhw  = (_Float16*)(ws + off_b);  off_b += NN * 2 * 2;       // 16 MB
  _Float16*  Blw  = (_Float16*)(ws + off_b);  off_b += NN * 2 * 2;       // 16 MB

  // ---- CSR build for both graphs ----
  k_zero<<<16, 256, 0, stream>>>(cnt_knn, 4096);  // cnt_knn & cnt_ppi adjacent
  k_count<<<(E_knn + 255) / 256, 256, 0, stream>>>(knn + E_knn, E_knn, cnt_knn);
  k_count<<<(E_ppi + 255) / 256, 256, 0, stream>>>(ppi + E_ppi, E_ppi, cnt_ppi);
  k_scan<<<2, 1024, 0, stream>>>(cnt_knn, off_knn, cur_knn, inv_knn, E_knn,
                                 cnt_ppi, off_ppi, cur_ppi, inv_ppi, E_ppi);
  k_fill<<<(E_knn + 255) / 256, 256, 0, stream>>>(knn, knn + E_knn, E_knn, cur_knn, src_knn);
  k_fill<<<(E_ppi + 255) / 256, 256, 0, stream>>>(ppi, ppi + E_ppi, E_ppi, cur_ppi, src_ppi);

  // ---- A = x^T [cell,gene] as fp16 hi/lo, linear ----
  {
    dim3 g(32, 32);
    k_transpose_cvt<<<g, 256, 0, stream>>>(x, Ahw, Alw);
  }

  for (int i = 0; i < NLAYERS; ++i) {
    dim3 gb(32, 32, 2);
    // cols side
    k_cvtB<<<gb, 256, 0, stream>>>(col_Wl + (size_t)i * NN, col_Wr + (size_t)i * NN, Bhw, Blw);
    k_gemm16r<<<512, 256, 0, stream>>>(Ahw, Alw, Bhw, Blw, Cbuf);
    k_fuse<<<1024, 256, 0, stream>>>(Cbuf, off_knn, src_knn, inv_knn,
                                     col_bl + (size_t)i * NSZ, out, Ahw, Alw, 1, E_knn);
    // rows side
    k_cvtB<<<gb, 256, 0, stream>>>(row_Wl + (size_t)i * NN, row_Wr + (size_t)i * NN, Bhw, Blw);
    k_gemm16r<<<512, 256, 0, stream>>>(Ahw, Alw, Bhw, Blw, Cbuf);
    // layers 0-2: fp16 split transposed (next cols-side A); layer 3: fp32 out
    k_fuse<<<1024, 256, 0, stream>>>(Cbuf, off_ppi, src_ppi, inv_ppi,
                                     row_bl + (size_t)i * NSZ, out, Ahw, Alw,
                                     (i < NLAYERS - 1) ? 1 : 0, E_ppi);
  }
}

// Round 8
// 1532.295 us; speedup vs baseline: 1.3211x; 1.3211x over previous
//
#include <hip/hip_runtime.h>
#include <stdint.h>

#define NSZ 2048
#define NLAYERS 4

typedef __attribute__((ext_vector_type(4))) float f32x4;
typedef __attribute__((ext_vector_type(4))) _Float16 f16x4;
typedef __attribute__((ext_vector_type(8))) _Float16 f16x8;

__device__ __forceinline__ void gload_lds16(const void* g, void* l) {
  __builtin_amdgcn_global_load_lds((const __attribute__((address_space(1))) void*)g,
                                   (__attribute__((address_space(3))) void*)l, 16, 0, 0);
}

// ---------------- CSR build ----------------
__global__ void k_zero(int* __restrict__ p, int n) {
  int i = blockIdx.x * 256 + threadIdx.x;
  if (i < n) p[i] = 0;
}

__global__ void k_count(const int* __restrict__ tgt, int E, int* __restrict__ cnt) {
  int e = blockIdx.x * 256 + threadIdx.x;
  if (e < E) atomicAdd(&cnt[tgt[e] & (NSZ - 1)], 1);
}

__global__ __launch_bounds__(1024) void k_scan(
    const int* __restrict__ cntA, int* __restrict__ offA, int* __restrict__ curA,
    float* __restrict__ invA, int EA,
    const int* __restrict__ cntB, int* __restrict__ offB, int* __restrict__ curB,
    float* __restrict__ invB, int EB) {
  const int* cnt; int* off; int* cur; float* inv; int E;
  if (blockIdx.x == 0) { cnt = cntA; off = offA; cur = curA; inv = invA; E = EA; }
  else                 { cnt = cntB; off = offB; cur = curB; inv = invB; E = EB; }
  __shared__ int sa[2048], sb[2048];
  int t = threadIdx.x;
  sa[t] = cnt[t]; sa[t + 1024] = cnt[t + 1024];
  __syncthreads();
  int* s = sa; int* d = sb;
  for (int dd = 1; dd < 2048; dd <<= 1) {
    for (int i = t; i < 2048; i += 1024)
      d[i] = s[i] + ((i >= dd) ? s[i - dd] : 0);
    __syncthreads();
    int* tmp = s; s = d; d = tmp;
  }
  for (int i = t; i < 2048; i += 1024) {
    int o = (i == 0) ? 0 : s[i - 1];
    off[i] = o; cur[i] = o;
    int c = cnt[i];
    inv[i] = 1.0f / (float)((c > 1) ? c : 1);
  }
  if (t == 0) off[2048] = E;
}

__global__ void k_fill(const int* __restrict__ src, const int* __restrict__ tgt, int E,
                       int* __restrict__ cur, int* __restrict__ srcs) {
  int e = blockIdx.x * 256 + threadIdx.x;
  if (e < E) {
    int p = atomicAdd(&cur[tgt[e] & (NSZ - 1)], 1);
    if (p >= 0 && p < E) srcs[p] = src[e] & (NSZ - 1);
  }
}

// ---------------- x [gene,cell] -> A = x^T [cell,gene] fp16 hi/lo, swizzled ----------------
__global__ __launch_bounds__(256) void k_transpose_cvt(const float* __restrict__ s,
                                                       _Float16* __restrict__ Ah,
                                                       _Float16* __restrict__ Al) {
  __shared__ float tile[64][65];
  const int tid = threadIdx.x;
  const int r0 = blockIdx.y << 6, c0 = blockIdx.x << 6;
#pragma unroll
  for (int it = 0; it < 4; ++it) {
    int e = it * 256 + tid;
    int r = e >> 4;
    int c = (e & 15) << 2;
    f32x4 v = *(const f32x4*)&s[(size_t)(r0 + r) * NSZ + c0 + c];
#pragma unroll
    for (int j = 0; j < 4; ++j) tile[r][c + j] = v[j];
  }
  __syncthreads();
#pragma unroll
  for (int it = 0; it < 4; ++it) {
    int e = it * 256 + tid;
    int r = e >> 4;           // output row within tile (m = cell)
    int c4 = (e & 15) << 2;   // output col chunk (k = gene)
    f16x4 hi, lo;
#pragma unroll
    for (int j = 0; j < 4; ++j) {
      float x = tile[c4 + j][r];
      _Float16 h = (_Float16)x;
      hi[j] = h;
      lo[j] = (_Float16)(x - (float)h);
    }
    int m = c0 + r;
    size_t rowb = (size_t)m << 12;
    int byte = ((r0 + c4) << 1) ^ (((m >> 1) & 3) << 4);
    *(f16x4*)((char*)Ah + rowb + byte) = hi;
    *(f16x4*)((char*)Al + rowb + byte) = lo;
  }
}

// ---------------- W [k][n] fp32 -> Bt [nbase+n][k] fp16 hi/lo, swizzled ----------------
__global__ __launch_bounds__(256) void k_cvtB(const float* __restrict__ Wl,
                                              const float* __restrict__ Wr,
                                              _Float16* __restrict__ Bh,
                                              _Float16* __restrict__ Bl) {
  __shared__ float tile[64][65];
  const float* W = blockIdx.z ? Wr : Wl;
  const int nbase = blockIdx.z ? NSZ : 0;
  const int tid = threadIdx.x;
  const int k0 = blockIdx.y << 6;   // input rows (k)
  const int n0 = blockIdx.x << 6;   // input cols (n)
#pragma unroll
  for (int it = 0; it < 4; ++it) {
    int e = it * 256 + tid;
    int r = e >> 4;
    int c = (e & 15) << 2;
    f32x4 v = *(const f32x4*)&W[(size_t)(k0 + r) * NSZ + n0 + c];
#pragma unroll
    for (int j = 0; j < 4; ++j) tile[r][c + j] = v[j];
  }
  __syncthreads();
#pragma unroll
  for (int it = 0; it < 4; ++it) {
    int e = it * 256 + tid;
    int r = e >> 4;            // n within tile (output row)
    int c4 = (e & 15) << 2;    // k within tile (output col chunk)
    f16x4 hi, lo;
#pragma unroll
    for (int j = 0; j < 4; ++j) {
      float x = tile[c4 + j][r];
      _Float16 h = (_Float16)x;
      hi[j] = h;
      lo[j] = (_Float16)(x - (float)h);
    }
    int n = nbase + n0 + r;
    size_t rowb = (size_t)n << 12;
    int byte = ((k0 + c4) << 1) ^ (((n >> 1) & 3) << 4);
    *(f16x4*)((char*)Bh + rowb + byte) = hi;
    *(f16x4*)((char*)Bl + rowb + byte) = lo;
  }
}

// ---------------- fp16x3 split MFMA GEMM, dbuf LDS + 4-phase interleave ----------------
// 128x128 tile, BK=32, 4 waves 2x2 (each 64x64 = 4x4 frags of 16x16x32_f16).
// C = Ah*Bh + Ah*Bl + Al*Bh, fp32 accumulate. Grid: 16 m-tiles x 32 n-tiles = 512.
// Per K-step: 4 phases {stage part | ds_read quadrant | 12 MFMA | s_barrier};
// single vmcnt(0) per K-step at loop top. Best measured: 94.1 us (R6).
__global__ __launch_bounds__(256, 2) void k_gemm16p(
    const _Float16* __restrict__ Ah, const _Float16* __restrict__ Al,
    const _Float16* __restrict__ Bh, const _Float16* __restrict__ Bl,
    float* __restrict__ C) {
  __shared__ __align__(128) _Float16 lds[2][4][128][32];  // 64 KB, double-buffered
  const int tid = threadIdx.x;
  const int w = tid >> 6;
  const int lane = tid & 63;
  int bid = blockIdx.x;
  bid = ((bid & 7) << 6) | (bid >> 3);     // bijective XCD swizzle (512 = 8*64)
  const int bm = bid & 15;
  const int bn = bid >> 4;
  const int m0 = bm << 7;
  const int n0 = bn << 7;
  const int wm = (w & 1) << 6;
  const int wn = (w >> 1) << 6;

  f32x4 acc[4][4];
#pragma unroll
  for (int i = 0; i < 4; ++i)
#pragma unroll
    for (int j = 0; j < 4; ++j)
#pragma unroll
      for (int r = 0; r < 4; ++r) acc[i][j][r] = 0.f;

  const int srow0 = (w << 5) + (lane >> 2);
  const int scol = (lane & 3) << 3;
  const int l15 = lane & 15;
  const int ks16 = (lane >> 4) << 4;

  const size_t aoff = (size_t)(m0 + srow0) * NSZ + scol;
  const size_t boff = (size_t)(n0 + srow0) * NSZ + scol;

#define SPART(buf, kk, p)                                                   \
  do {                                                                      \
    const int q_ = (p) >> 1;                                                \
    const size_t go_ = (size_t)(q_ << 4) * NSZ + (size_t)(kk);              \
    const int dr_ = ((w << 1) + q_) << 4;                                   \
    if (((p) & 1) == 0) {                                                   \
      gload_lds16(&Ah[aoff + go_], &lds[buf][0][dr_][0]);                   \
      gload_lds16(&Al[aoff + go_], &lds[buf][1][dr_][0]);                   \
    } else {                                                                \
      gload_lds16(&Bh[boff + go_], &lds[buf][2][dr_][0]);                   \
      gload_lds16(&Bl[boff + go_], &lds[buf][3][dr_][0]);                   \
    }                                                                       \
  } while (0)

#define RDA(f)                                                              \
  do {                                                                      \
    const int ra_ = wm + ((f) << 4) + l15;                                  \
    const int ca_ = ks16 ^ (((ra_ >> 1) & 3) << 4);                         \
    afh[f] = *(const f16x8*)((const char*)&lds[cur][0][ra_][0] + ca_);      \
    afl[f] = *(const f16x8*)((const char*)&lds[cur][1][ra_][0] + ca_);      \
  } while (0)

#define RDB(f)                                                              \
  do {                                                                      \
    const int rb_ = wn + ((f) << 4) + l15;                                  \
    const int cb_ = ks16 ^ (((rb_ >> 1) & 3) << 4);                         \
    bfh[f] = *(const f16x8*)((const char*)&lds[cur][2][rb_][0] + cb_);      \
    bfl[f] = *(const f16x8*)((const char*)&lds[cur][3][rb_][0] + cb_);      \
  } while (0)

#define TRIPLE(i, j)                                                                        \
  acc[i][j] = __builtin_amdgcn_mfma_f32_16x16x32_f16(afh[i], bfh[j], acc[i][j], 0, 0, 0);   \
  acc[i][j] = __builtin_amdgcn_mfma_f32_16x16x32_f16(afh[i], bfl[j], acc[i][j], 0, 0, 0);   \
  acc[i][j] = __builtin_amdgcn_mfma_f32_16x16x32_f16(afl[i], bfh[j], acc[i][j], 0, 0, 0);

#define QUAD(i0, j0)                                                        \
  TRIPLE(i0, j0) TRIPLE(i0, (j0) + 1) TRIPLE((i0) + 1, j0) TRIPLE((i0) + 1, (j0) + 1)

#define BAR() asm volatile("s_barrier" ::: "memory")
#define WAITVM0() asm volatile("s_waitcnt vmcnt(0)" ::: "memory")

  SPART(0, 0, 0); SPART(0, 0, 1); SPART(0, 0, 2); SPART(0, 0, 3);

  for (int t = 0; t < 63; ++t) {
    const int cur = t & 1;
    const int nxt = cur ^ 1;
    const int kn = (t + 1) << 5;
    WAITVM0();
    BAR();
    f16x8 afh[4], afl[4], bfh[4], bfl[4];
    // P0
    SPART(nxt, kn, 0); SPART(nxt, kn, 1);
    RDA(0); RDA(1); RDB(0); RDB(1);
    __builtin_amdgcn_s_setprio(1);
    QUAD(0, 0)
    __builtin_amdgcn_s_setprio(0);
    BAR();
    // P1
    SPART(nxt, kn, 2);
    RDB(2); RDB(3);
    __builtin_amdgcn_s_setprio(1);
    QUAD(0, 2)
    __builtin_amdgcn_s_setprio(0);
    BAR();
    // P2
    SPART(nxt, kn, 3);
    RDA(2); RDA(3);
    __builtin_amdgcn_s_setprio(1);
    QUAD(2, 2)
    __builtin_amdgcn_s_setprio(0);
    BAR();
    // P3
    __builtin_amdgcn_s_setprio(1);
    QUAD(2, 0)
    __builtin_amdgcn_s_setprio(0);
  }
  {
    const int cur = 1;
    WAITVM0();
    BAR();
    f16x8 afh[4], afl[4], bfh[4], bfl[4];
    RDA(0); RDA(1); RDB(0); RDB(1);
    QUAD(0, 0)
    RDB(2); RDB(3);
    QUAD(0, 2)
    RDA(2); RDA(3);
    QUAD(2, 2)
    QUAD(2, 0)
  }
#undef SPART
#undef RDA
#undef RDB
#undef TRIPLE
#undef QUAD
#undef BAR
#undef WAITVM0

  const int cr = (lane >> 4) << 2;
#pragma unroll
  for (int i = 0; i < 4; ++i)
#pragma unroll
    for (int j = 0; j < 4; ++j) {
      float* Cp = &C[(size_t)(m0 + wm + (i << 4) + cr) * 4096 + n0 + wn + (j << 4) + l15];
#pragma unroll
      for (int r = 0; r < 4; ++r) Cp[(size_t)r * 4096] = acc[i][j][r];
    }
}

// ---------------- fused mean-gather + self + bias + LeakyReLU ----------------
// XCD-pinned feature blocks. Gather: clamped-index predicated 8-batches (kept from
// R7: independent loads, ~-20us/dispatch). mode 1: fp16 hi/lo swizzled transposed
// (next GEMM's A); mode 0: fp32 nontemporal (final output).
__global__ __launch_bounds__(256) void k_fuse(const float* __restrict__ Cb,
                                              const int* __restrict__ off,
                                              const int* __restrict__ srcs,
                                              const float* __restrict__ inv,
                                              const float* __restrict__ bias,
                                              float* __restrict__ outF,
                                              _Float16* __restrict__ oh,
                                              _Float16* __restrict__ ol,
                                              int mode, int E) {
  __shared__ float tile[64][65];
  const int tid = threadIdx.x;
  const int w = tid >> 6;
  const int lane = tid & 63;
  const int lin = blockIdx.x;
  const int xcd = lin & 7;
  const int idx = lin >> 3;
  const int f0 = ((xcd << 2) | (idx & 3)) << 6;   // feature block: L2-resident per XCD
  const int t0 = (idx >> 2) << 6;                 // target block
  const int fc = f0 + lane;
  const float b = bias[fc];

  for (int it = 0; it < 16; ++it) {
    int lt = (w << 4) + it;
    int c = t0 + lt;
    int e0 = off[c], e1 = off[c + 1];
    if (e1 > E) e1 = E;
    if (e0 < 0) e0 = 0;
    float acc = 0.f;
    if (e0 < e1) {
      for (int e = e0; e < e1; e += 8) {
        float p[8];
#pragma unroll
        for (int q = 0; q < 8; ++q) {
          int ee = e + q;
          int ec = (ee < e1) ? ee : (e1 - 1);      // clamp: load always valid
          p[q] = Cb[(size_t)(srcs[ec] & (NSZ - 1)) * 4096 + fc];
        }
#pragma unroll
        for (int q = 0; q < 8; ++q) acc += ((e + q) < e1) ? p[q] : 0.f;
      }
    }
    float val = acc * inv[c] + Cb[(size_t)c * 4096 + 2048 + fc] + b;
    val = (val > 0.f) ? val : 0.01f * val;
    tile[lt][lane] = val;
  }
  __syncthreads();
  for (int it = 0; it < 4; ++it) {
    int f = it * 256 + tid;
    int r = f >> 4;
    int c4 = (f & 15) << 2;
    if (mode) {
      f16x4 hi, lo;
#pragma unroll
      for (int j = 0; j < 4; ++j) {
        float x = tile[c4 + j][r];
        _Float16 h = (_Float16)x;
        hi[j] = h;
        lo[j] = (_Float16)(x - (float)h);
      }
      int m = f0 + r;
      size_t rowb = (size_t)m << 12;
      int byte = ((t0 + c4) << 1) ^ (((m >> 1) & 3) << 4);
      *(f16x4*)((char*)oh + rowb + byte) = hi;
      *(f16x4*)((char*)ol + rowb + byte) = lo;
    } else {
      f32x4 v;
#pragma unroll
      for (int j = 0; j < 4; ++j) v[j] = tile[r][c4 + j];
      __builtin_nontemporal_store(v, (f32x4*)&outF[(size_t)(t0 + r) * NSZ + f0 + c4]);
    }
  }
}

extern "C" void kernel_launch(void* const* d_in, const int* in_sizes, int n_in,
                              void* d_out, int out_size, void* d_ws, size_t ws_size,
                              hipStream_t stream) {
  (void)n_in; (void)out_size; (void)ws_size;
  const float* x      = (const float*)d_in[0];
  const int*   knn    = (const int*)d_in[1];
  const int*   ppi    = (const int*)d_in[2];
  const float* col_Wl = (const float*)d_in[3];
  const float* col_bl = (const float*)d_in[4];
  const float* col_Wr = (const float*)d_in[5];
  const float* row_Wl = (const float*)d_in[6];
  const float* row_bl = (const float*)d_in[7];
  const float* row_Wr = (const float*)d_in[8];
  float* out = (float*)d_out;
  const int E_knn = in_sizes[1] / 2;
  const int E_ppi = in_sizes[2] / 2;
  const size_t NN = (size_t)NSZ * NSZ;

  // ---- workspace layout (~81 MB) ----
  char* ws = (char*)d_ws;
  size_t off_b = 0;
  int*   cnt_knn = (int*)(ws + off_b);   off_b += 2048 * 4;
  int*   cnt_ppi = (int*)(ws + off_b);   off_b += 2048 * 4;
  int*   off_knn = (int*)(ws + off_b);   off_b += 2064 * 4;
  int*   off_ppi = (int*)(ws + off_b);   off_b += 2064 * 4;
  int*   cur_knn = (int*)(ws + off_b);   off_b += 2048 * 4;
  int*   cur_ppi = (int*)(ws + off_b);   off_b += 2048 * 4;
  float* inv_knn = (float*)(ws + off_b); off_b += 2048 * 4;
  float* inv_ppi = (float*)(ws + off_b); off_b += 2048 * 4;
  int*   src_knn = (int*)(ws + off_b);   off_b += (size_t)((E_knn + 63) & ~63) * 4;
  int*   src_ppi = (int*)(ws + off_b);   off_b += (size_t)((E_ppi + 63) & ~63) * 4;
  off_b = (off_b + 255) & ~(size_t)255;
  float*     Cbuf = (float*)(ws + off_b);     off_b += NN * 2 * 4;       // 32 MB
  _Float16*  Ahw  = (_Float16*)(ws + off_b);  off_b += NN * 2;           // 8 MB
  _Float16*  Alw  = (_Float16*)(ws + off_b);  off_b += NN * 2;           // 8 MB
  _Float16*  Bhw  = (_Float16*)(ws + off_b);  off_b += NN * 2 * 2;       // 16 MB
  _Float16*  Blw  = (_Float16*)(ws + off_b);  off_b += NN * 2 * 2;       // 16 MB

  // ---- CSR build for both graphs ----
  k_zero<<<16, 256, 0, stream>>>(cnt_knn, 4096);  // cnt_knn & cnt_ppi adjacent
  k_count<<<(E_knn + 255) / 256, 256, 0, stream>>>(knn + E_knn, E_knn, cnt_knn);
  k_count<<<(E_ppi + 255) / 256, 256, 0, stream>>>(ppi + E_ppi, E_ppi, cnt_ppi);
  k_scan<<<2, 1024, 0, stream>>>(cnt_knn, off_knn, cur_knn, inv_knn, E_knn,
                                 cnt_ppi, off_ppi, cur_ppi, inv_ppi, E_ppi);
  k_fill<<<(E_knn + 255) / 256, 256, 0, stream>>>(knn, knn + E_knn, E_knn, cur_knn, src_knn);
  k_fill<<<(E_ppi + 255) / 256, 256, 0, stream>>>(ppi, ppi + E_ppi, E_ppi, cur_ppi, src_ppi);

  // ---- A = x^T [cell,gene] as fp16 hi/lo, swizzled ----
  {
    dim3 g(32, 32);
    k_transpose_cvt<<<g, 256, 0, stream>>>(x, Ahw, Alw);
  }

  for (int i = 0; i < NLAYERS; ++i) {
    dim3 gb(32, 32, 2);
    // cols side
    k_cvtB<<<gb, 256, 0, stream>>>(col_Wl + (size_t)i * NN, col_Wr + (size_t)i * NN, Bhw, Blw);
    k_gemm16p<<<512, 256, 0, stream>>>(Ahw, Alw, Bhw, Blw, Cbuf);
    k_fuse<<<1024, 256, 0, stream>>>(Cbuf, off_knn, src_knn, inv_knn,
                                     col_bl + (size_t)i * NSZ, out, Ahw, Alw, 1, E_knn);
    // rows side
    k_cvtB<<<gb, 256, 0, stream>>>(row_Wl + (size_t)i * NN, row_Wr + (size_t)i * NN, Bhw, Blw);
    k_gemm16p<<<512, 256, 0, stream>>>(Ahw, Alw, Bhw, Blw, Cbuf);
    // layers 0-2: fp16 split transposed (next cols-side A); layer 3: fp32 out
    k_fuse<<<1024, 256, 0, stream>>>(Cbuf, off_ppi, src_ppi, inv_ppi,
                                     row_bl + (size_t)i * NSZ, out, Ahw, Alw,
                                     (i < NLAYERS - 1) ? 1 : 0, E_ppi);
  }
}